// Round 12
// baseline (259.710 us; speedup 1.0000x reference)
//
#include <hip/hip_runtime.h>
#include <math.h>

#define BB 4
#define CH 256
#define CCH 64
#define HH 64
#define WW 64
#define HWN 4096

typedef short s8v __attribute__((ext_vector_type(8)));
typedef float f4v __attribute__((ext_vector_type(4)));

__device__ __forceinline__ float sigmoidf_(float v){ return 1.0f/(1.0f+__expf(-v)); }
__device__ __forceinline__ unsigned short f2bf(float f){
    union{float f; unsigned u;} v; v.f=f;
    unsigned r = v.u + 0x7FFF + ((v.u>>16)&1);
    return (unsigned short)(r>>16);
}
__device__ __forceinline__ float bf2f(unsigned short u){
    union{unsigned u; float f;} v; v.u = ((unsigned)u)<<16; return v.f;
}

// ---------------- K0: weight prep (w2 tap-major bf16 | bnp fold) ----------------
__global__ __launch_bounds__(256) void k_prepall(
    const float* __restrict__ wew, const float* __restrict__ wfw,
    const float* __restrict__ web, const float* __restrict__ weg, const float* __restrict__ webt,
    const float* __restrict__ wem, const float* __restrict__ wev,
    const float* __restrict__ wfb, const float* __restrict__ wfg, const float* __restrict__ wfbt,
    const float* __restrict__ wfm, const float* __restrict__ wfv,
    unsigned short* __restrict__ w2, float* __restrict__ bnp){
    int i = blockIdx.x*256+threadIdx.x;
    if (i < 294912){
        int row = i/576, k = i-row*576;
        int t = k>>6, ic = k&63;
        float v = (row<256)? wew[((row<<6)+ic)*9+t] : wfw[(((row-256)<<6)+ic)*9+t];
        w2[i] = f2bf(v);
        return;
    }
    int n = i - 294912;
    if (n < 256){
        float ie = weg[n]*rsqrtf(wev[n]+1e-5f);
        float se = webt[n]-wem[n]*ie+web[n]*ie;
        float iff = wfg[n]*rsqrtf(wfv[n]+1e-5f);
        float sf = wfbt[n]-wfm[n]*iff+wfb[n]*iff;
        *(float4*)(bnp+n*4) = make_float4(ie,se,iff,sf);
    }
}

// ---------------- K1: base_t bf16 [b][pos][c] = x+y (transposed) + per-(b,c) sums via atomics ----------------
// grid: b(4) x cb(4) x pb(64) = 1024 blocks
__global__ __launch_bounds__(256) void k_base_sum_t(const float* __restrict__ x, const float* __restrict__ y,
                                                    unsigned short* __restrict__ base_t, float* __restrict__ sums){
    int bid = blockIdx.x;
    int pb = bid&63, cb = (bid>>6)&3, b = bid>>8;
    int tid = threadIdx.x, lane = tid&63, w = tid>>6;
    __shared__ unsigned short lt[64*66];
    #pragma unroll
    for (int it=0; it<16; ++it){
        int c = it*4 + w;           // 0..63 (wave handles one channel per it)
        int p = lane;
        size_t gi = ((size_t)(b*256 + cb*64 + c))*4096 + pb*64 + p;
        float v = x[gi] + y[gi];
        lt[p*66 + c] = f2bf(v);
        float s = v;
        #pragma unroll
        for (int off=32; off; off>>=1) s += __shfl_down(s, off, 64);
        if (lane==0) atomicAdd(&sums[b*256 + cb*64 + c], s);
    }
    __syncthreads();
    #pragma unroll
    for (int it=0; it<8; ++it){
        int idx = it*256 + tid;     // 64 pos x 32 ch-pairs
        int p = idx>>5, cp = idx&31;
        unsigned lo = lt[p*66 + cp*2], hi = lt[p*66 + cp*2+1];
        *(unsigned*)(base_t + ((size_t)(b*4096 + pb*64 + p))*256 + cb*64 + cp*2) = lo | (hi<<16);
    }
}

// ---------------- K2: SE MLP -> scale = 1 + sigmoid(relu(mean@w1T)@w2T) ----------------
__global__ __launch_bounds__(256) void k_se(const float* __restrict__ sums, const float* __restrict__ w1,
                                            const float* __restrict__ w2, float* __restrict__ scale){
    int b = blockIdx.x, tid = threadIdx.x;
    __shared__ float sm[256];
    __shared__ float hid[16];
    sm[tid] = sums[b*256+tid]*(1.0f/4096.0f);
    __syncthreads();
    if (tid<16){
        float a=0.f; const float* wp = w1 + tid*256;
        for (int c=0;c<256;c++) a += sm[c]*wp[c];
        hid[tid]=fmaxf(a,0.f);
    }
    __syncthreads();
    float a=0.f; const float* wp = w2 + tid*16;
    #pragma unroll
    for (int j=0;j<16;j++) a += hid[j]*wp[j];
    scale[b*256+tid] = 1.f + sigmoidf_(a);
}

// ---------------- K3: per-batch SE-scaled weights (scale folded into GEMM A-side) ----------------
// wdcn_b[b][oc][k*256+c] = enc_w[oc][c*9+k]*s[b][c];  wofft_b[b][ko][k*256+c] = ow[ko][c][k]*s[b][c]
__global__ __launch_bounds__(256) void k_wscale(const float* __restrict__ enc_w, const float* __restrict__ ow,
                                                const float* __restrict__ scale,
                                                unsigned short* __restrict__ wdcn_b,
                                                unsigned short* __restrict__ wofft_b){
    int i = blockIdx.x*256+threadIdx.x;   // < 884736
    if (i < 589824){
        int b = i/147456, r = i-b*147456;
        int oc = r/2304, kk = r-oc*2304;
        int k = kk>>8, c = kk&255;
        wdcn_b[i] = f2bf(enc_w[(size_t)oc*2304 + c*9 + k] * scale[b*256+c]);
    } else {
        int j = i - 589824;
        int b = j/73728, r = j-b*73728;
        int ko = r/2304, kk = r-ko*2304;
        int k = kk>>8, c = kk&255;
        float v = (ko<27)? ow[(size_t)(ko*256+c)*9 + k] * scale[b*256+c] : 0.f;
        wofft_b[j] = f2bf(v);
    }
}

// ---------------- K4: offset conv via MFMA: C[32][64 pos], K=2304 tap-major ----------------
__global__ __launch_bounds__(512) void k_offconv_mfma(const unsigned short* __restrict__ base_t,
    const unsigned short* __restrict__ wofft_b, const float* __restrict__ ob, float* __restrict__ off){
    int bid = blockIdx.x;
    int tIdx = bid&63, b = bid>>6;
    int th = tIdx>>3, tw = tIdx&7;
    int tid = threadIdx.x;
    __shared__ unsigned short plds[3200*8];   // 100 spots x 256 ch bf16, XOR swizzle
    const unsigned short* bt = base_t + (((size_t)b)<<12)*256;
    for (int i=tid; i<3200; i+=512){
        int spot = i>>5, cid = i&31;
        int sy = spot/10, sx = spot - sy*10;
        int gy = th*8 + sy - 1, gx = tw*8 + sx - 1;
        uint4 v = make_uint4(0u,0u,0u,0u);
        if (gy>=0 && gy<HH && gx>=0 && gx<WW)
            v = *(const uint4*)(bt + ((size_t)((gy<<6)+gx))*256 + cid*8);
        int chunk = (spot<<5) | (cid ^ (spot&7));
        *(uint4*)(plds + (chunk<<3)) = v;
    }
    __syncthreads();
    int lane = tid&63, w = tid>>6;
    int rf = w&1, pf = w>>1;
    int col = lane&15, kg = lane>>4;
    int p = pf*16 + col, ly = p>>3, lx = p&7;
    f4v acc = (f4v){0.f,0.f,0.f,0.f};
    const unsigned short* wb = wofft_b + (size_t)b*73728;
    #pragma unroll
    for (int j=0;j<9;j++){
        int dy = j/3, dx = j%3;
        int spot = (ly+dy)*10 + lx+dx;
        const unsigned short* arow = wb + (size_t)(rf*16+col)*2304 + j*256 + kg*8;
        #pragma unroll
        for (int s=0;s<8;s++){
            s8v a = *(const s8v*)(arow + s*32);
            int cid = s*4 + kg;
            s8v bf = *(const s8v*)(plds + (((spot<<5)|(cid^(spot&7)))<<3));
            acc = __builtin_amdgcn_mfma_f32_16x16x32_bf16(a, bf, acc, 0,0,0);
        }
    }
    int gy = th*8+ly, gx = tw*8+lx;
    #pragma unroll
    for (int r=0;r<4;r++){
        int ko = rf*16 + kg*4 + r;
        if (ko < 27)
            off[(((size_t)(b*27+ko))<<12) + (gy<<6) + gx] = acc[r] + ob[ko];
    }
}

// ---------------- K5a: per-(b,k,pos) corner weights/indices ----------------
__global__ __launch_bounds__(256) void k_prep_off(const float* __restrict__ off,
                                                  float4* __restrict__ cwg, int4* __restrict__ cig){
    int i = blockIdx.x*256+threadIdx.x;   // < 4*9*4096
    if (i >= 147456) return;
    int b = i/36864, rem = i - b*36864;
    int k = rem>>12, pos = rem&4095;
    int h = pos>>6, p = pos&63;
    const float* op = off + ((size_t)b*27<<12) + pos;
    float dy = op[(size_t)(2*k)<<12];
    float dx = op[(size_t)(2*k+1)<<12];
    float m  = sigmoidf_(op[(size_t)(18+k)<<12]);
    float py = (float)(h + k/3 - 1) + dy;
    float px = (float)(p + (k%3) - 1) + dx;
    float y0 = floorf(py), x0 = floorf(px);
    float fy1 = py - y0, fy0 = 1.f - fy1;
    float fx1 = px - x0, fx0 = 1.f - fx1;
    int iy0 = (int)y0, ix0 = (int)x0;
    bool vy0 = (y0>=0.f)&&(y0<64.f), vy1 = (y0>=-1.f)&&(y0<63.f);
    bool vx0 = (x0>=0.f)&&(x0<64.f), vx1 = (x0>=-1.f)&&(x0<63.f);
    int cy0 = min(max(iy0,0),63), cy1 = min(max(iy0+1,0),63);
    int cx0 = min(max(ix0,0),63), cx1 = min(max(ix0+1,0),63);
    float4 wv; int4 iv;
    wv.x = (vy0&&vx0)? fy0*fx0*m : 0.f;
    wv.y = (vy0&&vx1)? fy0*fx1*m : 0.f;
    wv.z = (vy1&&vx0)? fy1*fx0*m : 0.f;
    wv.w = (vy1&&vx1)? fy1*fx1*m : 0.f;
    iv.x = cy0*WW+cx0; iv.y = cy0*WW+cx1; iv.z = cy1*WW+cx0; iv.w = cy1*WW+cx1;
    cwg[i] = wv; cig[i] = iv;
}

// ---------------- K5b: DCNv2 channel-contiguous sample + MFMA, split-K x4, XCD-pinned ----------------
__global__ __launch_bounds__(512) void k_dcn_mfma(const unsigned short* __restrict__ base_t,
    const float4* __restrict__ cwg, const int4* __restrict__ cig,
    const unsigned short* __restrict__ wdcn_b, unsigned short* __restrict__ part2b){
    int bid = blockIdx.x;
    int cg = bid&3, b = (bid>>2)&3, h = bid>>4;
    int tid = threadIdx.x;
    __shared__ float4 cw4[576];
    __shared__ int4   ci4[576];
    __shared__ unsigned short smp[2][4096];

    for (int i=tid;i<576;i+=512){
        int k = i>>6, p = i&63;
        size_t g = (((size_t)b*9 + k)<<12) + (h<<6) + p;
        cw4[i] = cwg[g];
        ci4[i] = cig[g];
    }
    __syncthreads();

    int pos = tid>>3, cv = tid&7;
    int w = tid>>6, lane = tid&63;
    int mf = w&3, nh = w>>2;
    int col = lane&15, kg = lane>>4;
    f4v acc0 = (f4v){0.f,0.f,0.f,0.f}, acc1 = acc0;
    const unsigned short* bt = base_t + (((size_t)b)<<12)*256 + cg*64 + cv*8;
    const unsigned short* wrow = wdcn_b + (size_t)b*147456 + (size_t)(mf*16+col)*2304 + cg*64;

    #pragma unroll
    for (int t=0;t<9;t++){
        float4 wv = cw4[t*64+pos];
        int4  iv = ci4[t*64+pos];
        uint4 r0 = *(const uint4*)(bt + ((size_t)iv.x<<8));
        uint4 r1 = *(const uint4*)(bt + ((size_t)iv.y<<8));
        uint4 r2 = *(const uint4*)(bt + ((size_t)iv.z<<8));
        uint4 r3 = *(const uint4*)(bt + ((size_t)iv.w<<8));
        const unsigned* q0=(const unsigned*)&r0;
        const unsigned* q1=(const unsigned*)&r1;
        const unsigned* q2=(const unsigned*)&r2;
        const unsigned* q3=(const unsigned*)&r3;
        unsigned pk[4];
        #pragma unroll
        for (int d=0;d<4;d++){
            float lo = wv.x*bf2f((unsigned short)(q0[d]&0xFFFFu)) + wv.y*bf2f((unsigned short)(q1[d]&0xFFFFu))
                     + wv.z*bf2f((unsigned short)(q2[d]&0xFFFFu)) + wv.w*bf2f((unsigned short)(q3[d]&0xFFFFu));
            float hi = wv.x*bf2f((unsigned short)(q0[d]>>16)) + wv.y*bf2f((unsigned short)(q1[d]>>16))
                     + wv.z*bf2f((unsigned short)(q2[d]>>16)) + wv.w*bf2f((unsigned short)(q3[d]>>16));
            pk[d] = (unsigned)f2bf(lo) | ((unsigned)f2bf(hi)<<16);
        }
        *(uint4*)(&smp[t&1][0] + (((pos<<3)|(cv^(pos&7)))<<3)) = *(const uint4*)pk;
        __syncthreads();
        const unsigned short* sb = &smp[t&1][0];
        #pragma unroll
        for (int ks=0;ks<2;ks++){
            s8v a = *(const s8v*)(wrow + t*256 + ks*32 + kg*8);
            int cgrp = ks*4+kg;
            int p0 = (nh*2)*16 + col;
            int p1 = p0 + 16;
            s8v b0 = *(const s8v*)(sb + (((p0<<3)|(cgrp^(p0&7)))<<3));
            s8v b1 = *(const s8v*)(sb + (((p1<<3)|(cgrp^(p1&7)))<<3));
            acc0 = __builtin_amdgcn_mfma_f32_16x16x32_bf16(a, b0, acc0, 0,0,0);
            acc1 = __builtin_amdgcn_mfma_f32_16x16x32_bf16(a, b1, acc1, 0,0,0);
        }
    }

    unsigned short* pout = part2b + ((size_t)(cg*BB + b))*(HWN*64);
    #pragma unroll
    for (int j=0;j<2;j++){
        f4v a = j ? acc1 : acc0;
        int posg = (h<<6) + (nh*2+j)*16 + col;
        int oc = mf*16 + kg*4;
        unsigned lo = (unsigned)f2bf(a[0]) | ((unsigned)f2bf(a[1])<<16);
        unsigned hi = (unsigned)f2bf(a[2]) | ((unsigned)f2bf(a[3])<<16);
        *(uint2*)(pout + (size_t)posg*64 + oc) = make_uint2(lo,hi);
    }
}

// ---------------- K5c: sum 4 bf16 partials + bias + relu -> enc_t bf16 [b][pos][oc] ----------------
__global__ __launch_bounds__(256) void k_encreduce(const unsigned short* __restrict__ part2b,
                                                   const float* __restrict__ encb,
                                                   unsigned short* __restrict__ enc_t){
    int i = blockIdx.x*256+threadIdx.x;   // < 4*4096*32
    int b = i>>17, rem = i&131071;
    int pos = rem>>5, oc2 = rem&31;
    size_t basei = (((size_t)b<<12) + pos)*64 + oc2*2;
    float s0 = encb[oc2*2], s1 = encb[oc2*2+1];
    #pragma unroll
    for (int cg=0;cg<4;cg++){
        unsigned pv = *(const unsigned*)(part2b + (size_t)cg*1048576 + basei);
        s0 += bf2f((unsigned short)(pv & 0xFFFFu));
        s1 += bf2f((unsigned short)(pv >> 16));
    }
    unsigned short lo = f2bf(fmaxf(s0,0.f));
    unsigned short hi = f2bf(fmaxf(s1,0.f));
    *(unsigned int*)(enc_t + basei) = (unsigned int)lo | ((unsigned int)hi<<16);
}

// ---------------- K6: fused gate convs via MFMA bf16 + BN + sigmoid + blend ----------------
// grid: b(4) x tile(16) x ocg(8) = 512 blocks, 512 thr; block: 64 rows (32 we + 32 wf) x 256 pos
__global__ __launch_bounds__(512) void k_fuse_mfma(const unsigned short* __restrict__ enc_t,
    const unsigned short* __restrict__ w2, const float* __restrict__ bnp,
    const float* __restrict__ x, const float* __restrict__ y, float* __restrict__ out){
    int bid = blockIdx.x;
    int ocg = bid&7, tile = (bid>>3)&15, b = bid>>7;
    int h0 = (tile>>2)<<4, w0 = (tile&3)<<4;
    int tid = threadIdx.x;
    __shared__ unsigned short elds[324*64];

    const unsigned short* ebase = enc_t + (((size_t)b)<<12)*64;
    #pragma unroll
    for (int kk=0;kk<6;kk++){
        int i = tid + kk*512;
        if (i < 2592){
            int sp = i>>3, icg = i&7;
            int sy = sp/18, sx = sp - sy*18;
            int py = h0+sy-1, px = w0+sx-1;
            uint4 v = make_uint4(0u,0u,0u,0u);
            if (py>=0 && py<HH && px>=0 && px<WW)
                v = *(const uint4*)(ebase + (size_t)((py<<6)+px)*64 + (icg<<3));
            int chunk = ((sp<<3) | icg) ^ (sp&7);
            *(uint4*)(elds + (chunk<<3)) = v;
        }
    }
    __syncthreads();

    int lane = tid&63, w = tid>>6;
    int col = lane&15, kg = lane>>4;
    f4v acc[4][2];
    #pragma unroll
    for (int rf=0;rf<4;rf++)
        #pragma unroll
        for (int pf=0;pf<2;pf++) acc[rf][pf] = (f4v){0.f,0.f,0.f,0.f};

    #pragma unroll
    for (int t=0;t<18;t++){
        const int j = t>>1, ih = t&1;
        const int dy = j/3-1, dx = j%3-1;
        s8v af[4];
        #pragma unroll
        for (int rf=0;rf<4;rf++){
            int row = (rf<2 ? ocg*32 + rf*16 : 256 + ocg*32 + (rf-2)*16) + col;
            af[rf] = *(const s8v*)(w2 + (size_t)row*576 + t*32 + kg*8);
        }
        s8v bfr[2];
        #pragma unroll
        for (int pf=0;pf<2;pf++){
            int tyc = w*2+pf;
            int sp = (tyc+dy+1)*18 + (col+dx+1);
            int chunk = ((sp<<3) | (ih*4+kg)) ^ (sp&7);
            bfr[pf] = *(const s8v*)(elds + (chunk<<3));
        }
        #pragma unroll
        for (int rf=0;rf<4;rf++)
            #pragma unroll
            for (int pf=0;pf<2;pf++)
                acc[rf][pf] = __builtin_amdgcn_mfma_f32_16x16x32_bf16(af[rf], bfr[pf], acc[rf][pf], 0,0,0);
    }

    #pragma unroll
    for (int rf=0;rf<2;rf++){
        #pragma unroll
        for (int pf=0;pf<2;pf++){
            int tyc = w*2+pf;
            int py = h0+tyc, px = w0+col;
            #pragma unroll
            for (int r=0;r<4;r++){
                int oc = ocg*32 + rf*16 + kg*4 + r;
                float4 bn = *(const float4*)(bnp + oc*4);
                float ve = sigmoidf_(acc[rf  ][pf][r]*bn.x + bn.y);
                float vf = sigmoidf_(acc[rf+2][pf][r]*bn.z + bn.w);
                size_t oi = (((size_t)((b<<8)+oc))<<12) + (py<<6) + px;
                out[oi] = ve*x[oi] + vf*y[oi];
            }
        }
    }
}

extern "C" void kernel_launch(void* const* d_in, const int* in_sizes, int n_in,
                              void* d_out, int out_size, void* d_ws, size_t ws_size,
                              hipStream_t stream) {
    const float* x     = (const float*)d_in[0];
    const float* y     = (const float*)d_in[1];
    const float* se_w1 = (const float*)d_in[2];
    const float* se_w2 = (const float*)d_in[3];
    const float* off_w = (const float*)d_in[4];
    const float* off_b = (const float*)d_in[5];
    const float* enc_w = (const float*)d_in[6];
    const float* enc_b = (const float*)d_in[7];
    const float* we_w  = (const float*)d_in[8];
    const float* we_b  = (const float*)d_in[9];
    const float* we_g  = (const float*)d_in[10];
    const float* we_bt = (const float*)d_in[11];
    const float* we_m  = (const float*)d_in[12];
    const float* we_v  = (const float*)d_in[13];
    const float* wf_w  = (const float*)d_in[14];
    const float* wf_b  = (const float*)d_in[15];
    const float* wf_g  = (const float*)d_in[16];
    const float* wf_bt = (const float*)d_in[17];
    const float* wf_m  = (const float*)d_in[18];
    const float* wf_v  = (const float*)d_in[19];
    float* out = (float*)d_out;

    float* ws      = (float*)d_ws;
    float* off     = ws;                        // 442368 f
    float* encT_f  = off + 442368;              // 524288 f (1048576 ush)
    float* sums    = encT_f + 524288;           // 1024 f
    float* scale   = sums + 1024;               // 1024 f
    float* w2f     = scale + 1024;              // 147456 f (294912 ush)
    float* bnp     = w2f + 147456;              // 1024 f
    float* wdcnb_f = bnp + 1024;                // 294912 f (589824 ush)
    float* wofftb_f= wdcnb_f + 294912;          // 147456 f (294912 ush)
    float* cw_f    = wofftb_f + 147456;         // 589824 f (147456 float4)
    float* ci_f    = cw_f + 589824;             // 589824 f (147456 int4)
    unsigned short* enc_t   = (unsigned short*)encT_f;
    unsigned short* w2      = (unsigned short*)w2f;
    unsigned short* wdcn_b  = (unsigned short*)wdcnb_f;
    unsigned short* wofft_b = (unsigned short*)wofftb_f;
    float4* cwg = (float4*)cw_f;
    int4*   cig = (int4*)ci_f;
    // d_out scratch, two disjoint 8.39MB halves:
    unsigned short* base_t = (unsigned short*)out;            // k_base_sum_t -> k_offconv/k_dcn
    unsigned short* part2b = (unsigned short*)out + 4194304;  // k_dcn -> k_encreduce

    hipMemsetAsync(sums, 0, 1024*sizeof(float), stream);
    k_prepall     <<<1153, 256, 0, stream>>>(we_w, wf_w,
                                             we_b, we_g, we_bt, we_m, we_v,
                                             wf_b, wf_g, wf_bt, wf_m, wf_v, w2, bnp);
    k_base_sum_t  <<<1024, 256, 0, stream>>>(x, y, base_t, sums);
    k_se          <<<4,    256, 0, stream>>>(sums, se_w1, se_w2, scale);
    k_wscale      <<<3456, 256, 0, stream>>>(enc_w, off_w, scale, wdcn_b, wofft_b);
    k_offconv_mfma<<<256,  512, 0, stream>>>(base_t, wofft_b, off_b, off);
    k_prep_off    <<<576,  256, 0, stream>>>(off, cwg, cig);
    k_dcn_mfma    <<<1024, 512, 0, stream>>>(base_t, cwg, cig, wdcn_b, part2b);
    k_encreduce   <<<2048, 256, 0, stream>>>(part2b, enc_b, enc_t);
    k_fuse_mfma   <<<512,  512, 0, stream>>>(enc_t, w2, bnp, x, y, out);
}

// Round 13
// 259.534 us; speedup vs baseline: 1.0007x; 1.0007x over previous
//
#include <hip/hip_runtime.h>
#include <math.h>

#define BB 4
#define CH 256
#define CCH 64
#define HH 64
#define WW 64
#define HWN 4096

typedef short s8v __attribute__((ext_vector_type(8)));
typedef float f4v __attribute__((ext_vector_type(4)));

__device__ __forceinline__ float sigmoidf_(float v){ return 1.0f/(1.0f+__expf(-v)); }
__device__ __forceinline__ unsigned short f2bf(float f){
    union{float f; unsigned u;} v; v.f=f;
    unsigned r = v.u + 0x7FFF + ((v.u>>16)&1);
    return (unsigned short)(r>>16);
}
__device__ __forceinline__ float bf2f(unsigned short u){
    union{unsigned u; float f;} v; v.u = ((unsigned)u)<<16; return v.f;
}

// ---------------- K0: ALL weight prep fused (wdcn tap-major | w2 | wofft | bnp) ----------------
__global__ __launch_bounds__(256) void k_prepall(const float* __restrict__ enc_w,
    const float* __restrict__ wew, const float* __restrict__ wfw, const float* __restrict__ ow,
    const float* __restrict__ web, const float* __restrict__ weg, const float* __restrict__ webt,
    const float* __restrict__ wem, const float* __restrict__ wev,
    const float* __restrict__ wfb, const float* __restrict__ wfg, const float* __restrict__ wfbt,
    const float* __restrict__ wfm, const float* __restrict__ wfv,
    unsigned short* __restrict__ wdcn, unsigned short* __restrict__ w2,
    unsigned short* __restrict__ wofft, float* __restrict__ bnp){
    int i = blockIdx.x*256+threadIdx.x;
    if (i < 147456){
        int oc = i/2304, kk = i-oc*2304;
        int k = kk>>8, c = kk&255;
        wdcn[i] = f2bf(enc_w[(size_t)oc*2304 + c*9 + k]);
        return;
    }
    int j = i - 147456;
    if (j < 294912){
        int row = j/576, k = j-row*576;
        int t = k>>6, ic = k&63;
        float v = (row<256)? wew[((row<<6)+ic)*9+t] : wfw[(((row-256)<<6)+ic)*9+t];
        w2[j] = f2bf(v);
        return;
    }
    int m = j - 294912;
    if (m < 73728){
        int ko = m/2304, k = m-ko*2304;
        int t = k>>8, c = k&255;
        wofft[m] = f2bf((ko<27)? ow[(size_t)(ko*256+c)*9+t] : 0.f);
        return;
    }
    int n = m - 73728;
    if (n < 256){
        float ie = weg[n]*rsqrtf(wev[n]+1e-5f);
        float se = webt[n]-wem[n]*ie+web[n]*ie;
        float iff = wfg[n]*rsqrtf(wfv[n]+1e-5f);
        float sf = wfbt[n]-wfm[n]*iff+wfb[n]*iff;
        *(float4*)(bnp+n*4) = make_float4(ie,se,iff,sf);
    }
}

// ---------------- K1: base = x+y, per-(b,c) sum ----------------
__global__ __launch_bounds__(256) void k_base_sum(const float* __restrict__ x, const float* __restrict__ y,
                                                  float* __restrict__ base, float* __restrict__ sums){
    int bc = blockIdx.x, tid = threadIdx.x;
    const float* xp = x + (size_t)bc*HWN;
    const float* yp = y + (size_t)bc*HWN;
    float* bp = base + (size_t)bc*HWN;
    float s = 0.f;
    for (int i=tid;i<HWN;i+=256){ float v = xp[i]+yp[i]; bp[i]=v; s+=v; }
    __shared__ float red[256];
    red[tid]=s; __syncthreads();
    for (int off=128; off>0; off>>=1){ if (tid<off) red[tid]+=red[tid+off]; __syncthreads(); }
    if (tid==0) sums[bc]=red[0];
}

// ---------------- K2: SE MLP -> scale = 1 + sigmoid(relu(mean@w1T)@w2T) ----------------
__global__ __launch_bounds__(256) void k_se(const float* __restrict__ sums, const float* __restrict__ w1,
                                            const float* __restrict__ w2, float* __restrict__ scale){
    int b = blockIdx.x, tid = threadIdx.x;
    __shared__ float sm[256];
    __shared__ float hid[16];
    sm[tid] = sums[b*256+tid]*(1.0f/4096.0f);
    __syncthreads();
    if (tid<16){
        float a=0.f; const float* wp = w1 + tid*256;
        for (int c=0;c<256;c++) a += sm[c]*wp[c];
        hid[tid]=fmaxf(a,0.f);
    }
    __syncthreads();
    float a=0.f; const float* wp = w2 + tid*16;
    #pragma unroll
    for (int j=0;j<16;j++) a += hid[j]*wp[j];
    scale[b*256+tid] = 1.f + sigmoidf_(a);
}

// ---------------- K3: emit base_t bf16 [b][pos][c] = base*scale ----------------
__global__ __launch_bounds__(256) void k_scale_t(const float* __restrict__ base, const float* __restrict__ scale,
                                                 unsigned short* __restrict__ base_t){
    int bid = blockIdx.x;
    int pb = bid&63, cb = (bid>>6)&3, b = bid>>8;
    int tid = threadIdx.x;
    __shared__ unsigned short lt[64*66];
    #pragma unroll
    for (int it=0; it<16; ++it){
        int idx = it*256 + tid;
        int c = idx>>6, p = idx&63;
        size_t gi = ((size_t)(b*256 + cb*64 + c))*4096 + pb*64 + p;
        float v = base[gi] * scale[b*256 + cb*64 + c];
        lt[p*66 + c] = f2bf(v);
    }
    __syncthreads();
    #pragma unroll
    for (int it=0; it<8; ++it){
        int idx = it*256 + tid;   // 0..2047: 64 pos x 32 ch-pairs
        int p = idx>>5, cp = idx&31;
        unsigned lo = lt[p*66 + cp*2], hi = lt[p*66 + cp*2+1];
        *(unsigned*)(base_t + ((size_t)(b*4096 + pb*64 + p))*256 + cb*64 + cp*2) = lo | (hi<<16);
    }
}

// ---------------- K4: offset conv via MFMA: C[32][64 pos], K=2304 tap-major ----------------
__global__ __launch_bounds__(512) void k_offconv_mfma(const unsigned short* __restrict__ base_t,
    const unsigned short* __restrict__ wofft, const float* __restrict__ ob, float* __restrict__ off){
    int bid = blockIdx.x;
    int tIdx = bid&63, b = bid>>6;
    int th = tIdx>>3, tw = tIdx&7;
    int tid = threadIdx.x;
    __shared__ unsigned short plds[3200*8];
    const unsigned short* bt = base_t + (((size_t)b)<<12)*256;
    for (int i=tid; i<3200; i+=512){
        int spot = i>>5, cid = i&31;
        int sy = spot/10, sx = spot - sy*10;
        int gy = th*8 + sy - 1, gx = tw*8 + sx - 1;
        uint4 v = make_uint4(0u,0u,0u,0u);
        if (gy>=0 && gy<HH && gx>=0 && gx<WW)
            v = *(const uint4*)(bt + ((size_t)((gy<<6)+gx))*256 + cid*8);
        int chunk = (spot<<5) | (cid ^ (spot&7));
        *(uint4*)(plds + (chunk<<3)) = v;
    }
    __syncthreads();
    int lane = tid&63, w = tid>>6;
    int rf = w&1, pf = w>>1;
    int col = lane&15, kg = lane>>4;
    int p = pf*16 + col, ly = p>>3, lx = p&7;
    f4v acc = (f4v){0.f,0.f,0.f,0.f};
    #pragma unroll
    for (int j=0;j<9;j++){
        int dy = j/3, dx = j%3;
        int spot = (ly+dy)*10 + lx+dx;
        const unsigned short* arow = wofft + (size_t)(rf*16+col)*2304 + j*256 + kg*8;
        #pragma unroll
        for (int s=0;s<8;s++){
            s8v a = *(const s8v*)(arow + s*32);
            int cid = s*4 + kg;
            s8v bf = *(const s8v*)(plds + (((spot<<5)|(cid^(spot&7)))<<3));
            acc = __builtin_amdgcn_mfma_f32_16x16x32_bf16(a, bf, acc, 0,0,0);
        }
    }
    int gy = th*8+ly, gx = tw*8+lx;
    #pragma unroll
    for (int r=0;r<4;r++){
        int ko = rf*16 + kg*4 + r;
        if (ko < 27)
            off[(((size_t)(b*27+ko))<<12) + (gy<<6) + gx] = acc[r] + ob[ko];
    }
}

// ---------------- K5a: per-(b,k,pos) corner weights/indices ----------------
__global__ __launch_bounds__(256) void k_prep_off(const float* __restrict__ off,
                                                  float4* __restrict__ cwg, int4* __restrict__ cig){
    int i = blockIdx.x*256+threadIdx.x;
    if (i >= 147456) return;
    int b = i/36864, rem = i - b*36864;
    int k = rem>>12, pos = rem&4095;
    int h = pos>>6, p = pos&63;
    const float* op = off + ((size_t)b*27<<12) + pos;
    float dy = op[(size_t)(2*k)<<12];
    float dx = op[(size_t)(2*k+1)<<12];
    float m  = sigmoidf_(op[(size_t)(18+k)<<12]);
    float py = (float)(h + k/3 - 1) + dy;
    float px = (float)(p + (k%3) - 1) + dx;
    float y0 = floorf(py), x0 = floorf(px);
    float fy1 = py - y0, fy0 = 1.f - fy1;
    float fx1 = px - x0, fx0 = 1.f - fx1;
    int iy0 = (int)y0, ix0 = (int)x0;
    bool vy0 = (y0>=0.f)&&(y0<64.f), vy1 = (y0>=-1.f)&&(y0<63.f);
    bool vx0 = (x0>=0.f)&&(x0<64.f), vx1 = (x0>=-1.f)&&(x0<63.f);
    int cy0 = min(max(iy0,0),63), cy1 = min(max(iy0+1,0),63);
    int cx0 = min(max(ix0,0),63), cx1 = min(max(ix0+1,0),63);
    float4 wv; int4 iv;
    wv.x = (vy0&&vx0)? fy0*fx0*m : 0.f;
    wv.y = (vy0&&vx1)? fy0*fx1*m : 0.f;
    wv.z = (vy1&&vx0)? fy1*fx0*m : 0.f;
    wv.w = (vy1&&vx1)? fy1*fx1*m : 0.f;
    iv.x = cy0*WW+cx0; iv.y = cy0*WW+cx1; iv.z = cy1*WW+cx0; iv.w = cy1*WW+cx1;
    cwg[i] = wv; cig[i] = iv;
}

// ---------------- K5b: DCNv2 channel-contiguous sample + MFMA, split-K x4 ----------------
__global__ __launch_bounds__(512) void k_dcn_mfma(const unsigned short* __restrict__ base_t,
    const float4* __restrict__ cwg, const int4* __restrict__ cig,
    const unsigned short* __restrict__ wdcn, unsigned short* __restrict__ part2b){
    int bid = blockIdx.x;
    int cg = bid&3, b = (bid>>2)&3, h = bid>>4;
    int tid = threadIdx.x;
    __shared__ float4 cw4[576];
    __shared__ int4   ci4[576];
    __shared__ unsigned short smp[2][4096];

    for (int i=tid;i<576;i+=512){
        int k = i>>6, p = i&63;
        size_t g = (((size_t)b*9 + k)<<12) + (h<<6) + p;
        cw4[i] = cwg[g];
        ci4[i] = cig[g];
    }
    __syncthreads();

    int pos = tid>>3, cv = tid&7;
    int w = tid>>6, lane = tid&63;
    int mf = w&3, nh = w>>2;
    int col = lane&15, kg = lane>>4;
    f4v acc0 = (f4v){0.f,0.f,0.f,0.f}, acc1 = acc0;
    const unsigned short* bt = base_t + (((size_t)b)<<12)*256 + cg*64 + cv*8;
    const unsigned short* wrow = wdcn + (size_t)(mf*16+col)*2304 + cg*64;

    #pragma unroll
    for (int t=0;t<9;t++){
        float4 wv = cw4[t*64+pos];
        int4  iv = ci4[t*64+pos];
        uint4 r0 = *(const uint4*)(bt + ((size_t)iv.x<<8));
        uint4 r1 = *(const uint4*)(bt + ((size_t)iv.y<<8));
        uint4 r2 = *(const uint4*)(bt + ((size_t)iv.z<<8));
        uint4 r3 = *(const uint4*)(bt + ((size_t)iv.w<<8));
        const unsigned* q0=(const unsigned*)&r0;
        const unsigned* q1=(const unsigned*)&r1;
        const unsigned* q2=(const unsigned*)&r2;
        const unsigned* q3=(const unsigned*)&r3;
        unsigned pk[4];
        #pragma unroll
        for (int d=0;d<4;d++){
            float lo = wv.x*bf2f((unsigned short)(q0[d]&0xFFFFu)) + wv.y*bf2f((unsigned short)(q1[d]&0xFFFFu))
                     + wv.z*bf2f((unsigned short)(q2[d]&0xFFFFu)) + wv.w*bf2f((unsigned short)(q3[d]&0xFFFFu));
            float hi = wv.x*bf2f((unsigned short)(q0[d]>>16)) + wv.y*bf2f((unsigned short)(q1[d]>>16))
                     + wv.z*bf2f((unsigned short)(q2[d]>>16)) + wv.w*bf2f((unsigned short)(q3[d]>>16));
            pk[d] = (unsigned)f2bf(lo) | ((unsigned)f2bf(hi)<<16);
        }
        *(uint4*)(&smp[t&1][0] + (((pos<<3)|(cv^(pos&7)))<<3)) = *(const uint4*)pk;
        __syncthreads();
        const unsigned short* sb = &smp[t&1][0];
        #pragma unroll
        for (int ks=0;ks<2;ks++){
            s8v a = *(const s8v*)(wrow + t*256 + ks*32 + kg*8);
            int cgrp = ks*4+kg;
            int p0 = (nh*2)*16 + col;
            int p1 = p0 + 16;
            s8v b0 = *(const s8v*)(sb + (((p0<<3)|(cgrp^(p0&7)))<<3));
            s8v b1 = *(const s8v*)(sb + (((p1<<3)|(cgrp^(p1&7)))<<3));
            acc0 = __builtin_amdgcn_mfma_f32_16x16x32_bf16(a, b0, acc0, 0,0,0);
            acc1 = __builtin_amdgcn_mfma_f32_16x16x32_bf16(a, b1, acc1, 0,0,0);
        }
    }

    unsigned short* pout = part2b + ((size_t)(cg*BB + b))*(HWN*64);
    #pragma unroll
    for (int j=0;j<2;j++){
        f4v a = j ? acc1 : acc0;
        int posg = (h<<6) + (nh*2+j)*16 + col;
        int oc = mf*16 + kg*4;
        unsigned lo = (unsigned)f2bf(a[0]) | ((unsigned)f2bf(a[1])<<16);
        unsigned hi = (unsigned)f2bf(a[2]) | ((unsigned)f2bf(a[3])<<16);
        *(uint2*)(pout + (size_t)posg*64 + oc) = make_uint2(lo,hi);
    }
}

// ---------------- K5c: sum 4 bf16 partials + bias + relu -> enc_t bf16 [b][pos][oc] ----------------
__global__ __launch_bounds__(256) void k_encreduce(const unsigned short* __restrict__ part2b,
                                                   const float* __restrict__ encb,
                                                   unsigned short* __restrict__ enc_t){
    int i = blockIdx.x*256+threadIdx.x;
    int b = i>>17, rem = i&131071;
    int pos = rem>>5, oc2 = rem&31;
    size_t basei = (((size_t)b<<12) + pos)*64 + oc2*2;
    float s0 = encb[oc2*2], s1 = encb[oc2*2+1];
    #pragma unroll
    for (int cg=0;cg<4;cg++){
        unsigned pv = *(const unsigned*)(part2b + (size_t)cg*1048576 + basei);
        s0 += bf2f((unsigned short)(pv & 0xFFFFu));
        s1 += bf2f((unsigned short)(pv >> 16));
    }
    unsigned short lo = f2bf(fmaxf(s0,0.f));
    unsigned short hi = f2bf(fmaxf(s1,0.f));
    *(unsigned int*)(enc_t + basei) = (unsigned int)lo | ((unsigned int)hi<<16);
}

// ---------------- K6: fused gate convs via MFMA, 8x8 tiles, 2048 blocks ----------------
// grid: b(4) x tile(64: 8x8 of 8x8-pos) x ocg(8) = 2048 blocks, 256 thr (4 waves)
// block: 64 rows (32 we + 32 wf) x 64 pos, K=576 tap-major; wave = pos-frag
__global__ __launch_bounds__(256) void k_fuse_mfma(const unsigned short* __restrict__ enc_t,
    const unsigned short* __restrict__ w2, const float* __restrict__ bnp,
    const float* __restrict__ x, const float* __restrict__ y, float* __restrict__ out){
    int bid = blockIdx.x;
    int ocg = bid&7, tIdx = (bid>>3)&63, b = bid>>9;
    int th = tIdx>>3, tw = tIdx&7;
    int tid = threadIdx.x;
    __shared__ unsigned short elds[6400];   // 100 spots x 64 ch bf16 = 12.8KB, XOR swizzle

    const unsigned short* ebase = enc_t + (((size_t)b)<<12)*64;
    for (int i=tid; i<800; i+=256){
        int spot = i>>3, icg = i&7;
        int sy = spot/10, sx = spot - sy*10;
        int gy = th*8 + sy - 1, gx = tw*8 + sx - 1;
        uint4 v = make_uint4(0u,0u,0u,0u);
        if (gy>=0 && gy<HH && gx>=0 && gx<WW)
            v = *(const uint4*)(ebase + (size_t)((gy<<6)+gx)*64 + (icg<<3));
        int chunk = (spot<<3) | (icg ^ (spot&7));
        *(uint4*)(elds + (chunk<<3)) = v;
    }
    __syncthreads();

    int lane = tid&63, w = tid>>6;
    int col = lane&15, kg = lane>>4;
    int p = w*16 + col, ly = p>>3, lx = p&7;
    f4v acc[4];
    #pragma unroll
    for (int rf=0;rf<4;rf++) acc[rf] = (f4v){0.f,0.f,0.f,0.f};

    #pragma unroll
    for (int t=0;t<18;t++){
        const int j = t>>1, ih = t&1;
        const int dy = j/3, dx = j%3;
        int spot = (ly+dy)*10 + lx+dx;
        int cgrp = ih*4+kg;
        s8v bfr = *(const s8v*)(elds + (((spot<<3)|(cgrp^(spot&7)))<<3));
        #pragma unroll
        for (int rf=0;rf<4;rf++){
            int row = (rf<2 ? ocg*32 + rf*16 : 256 + ocg*32 + (rf-2)*16) + col;
            s8v a = *(const s8v*)(w2 + (size_t)row*576 + t*32 + kg*8);
            acc[rf] = __builtin_amdgcn_mfma_f32_16x16x32_bf16(a, bfr, acc[rf], 0,0,0);
        }
    }

    int gy = th*8+ly, gx = tw*8+lx;
    #pragma unroll
    for (int rf=0;rf<2;rf++){
        #pragma unroll
        for (int r=0;r<4;r++){
            int oc = ocg*32 + rf*16 + kg*4 + r;
            float4 bn = *(const float4*)(bnp + oc*4);
            float ve = sigmoidf_(acc[rf  ][r]*bn.x + bn.y);
            float vf = sigmoidf_(acc[rf+2][r]*bn.z + bn.w);
            size_t oi = (((size_t)((b<<8)+oc))<<12) + (gy<<6) + gx;
            out[oi] = ve*x[oi] + vf*y[oi];
        }
    }
}

extern "C" void kernel_launch(void* const* d_in, const int* in_sizes, int n_in,
                              void* d_out, int out_size, void* d_ws, size_t ws_size,
                              hipStream_t stream) {
    const float* x     = (const float*)d_in[0];
    const float* y     = (const float*)d_in[1];
    const float* se_w1 = (const float*)d_in[2];
    const float* se_w2 = (const float*)d_in[3];
    const float* off_w = (const float*)d_in[4];
    const float* off_b = (const float*)d_in[5];
    const float* enc_w = (const float*)d_in[6];
    const float* enc_b = (const float*)d_in[7];
    const float* we_w  = (const float*)d_in[8];
    const float* we_b  = (const float*)d_in[9];
    const float* we_g  = (const float*)d_in[10];
    const float* we_bt = (const float*)d_in[11];
    const float* we_m  = (const float*)d_in[12];
    const float* we_v  = (const float*)d_in[13];
    const float* wf_w  = (const float*)d_in[14];
    const float* wf_b  = (const float*)d_in[15];
    const float* wf_g  = (const float*)d_in[16];
    const float* wf_bt = (const float*)d_in[17];
    const float* wf_m  = (const float*)d_in[18];
    const float* wf_v  = (const float*)d_in[19];
    float* out = (float*)d_out;

    float* ws     = (float*)d_ws;
    float* base   = ws;                       // 4194304 f
    float* off    = base + 4194304;           // 442368 f
    float* encT_f = off  + 442368;            // 524288 f (1048576 ush)
    float* sums   = encT_f + 524288;          // 1024 f
    float* scale  = sums + 1024;              // 1024 f
    float* wdcn_f = scale + 1024;             // 73728 f (147456 ush)
    float* w2f    = wdcn_f + 73728;           // 147456 f (294912 ush)
    float* bnp    = w2f  + 147456;            // 1024 f
    float* wofft_f= bnp  + 1024;              // 36864 f (73728 ush)
    float* cw_f   = wofft_f + 36864;          // 589824 f (147456 float4)
    float* ci_f   = cw_f + 589824;            // 589824 f (147456 int4)
    unsigned short* enc_t = (unsigned short*)encT_f;
    unsigned short* wdcn  = (unsigned short*)wdcn_f;
    unsigned short* w2    = (unsigned short*)w2f;
    unsigned short* wofft = (unsigned short*)wofft_f;
    float4* cwg = (float4*)cw_f;
    int4*   cig = (int4*)ci_f;
    // d_out scratch, two disjoint 8.39MB halves:
    unsigned short* base_t = (unsigned short*)out;            // k_scale_t -> k_offconv/k_dcn
    unsigned short* part2b = (unsigned short*)out + 4194304;  // k_dcn -> k_encreduce

    k_prepall     <<<2018, 256, 0, stream>>>(enc_w, we_w, wf_w, off_w,
                                             we_b, we_g, we_bt, we_m, we_v,
                                             wf_b, wf_g, wf_bt, wf_m, wf_v,
                                             wdcn, w2, wofft, bnp);
    k_base_sum    <<<1024, 256, 0, stream>>>(x, y, base, sums);
    k_se          <<<4,    256, 0, stream>>>(sums, se_w1, se_w2, scale);
    k_scale_t     <<<1024, 256, 0, stream>>>(base, scale, base_t);
    k_offconv_mfma<<<256,  512, 0, stream>>>(base_t, wofft, off_b, off);
    k_prep_off    <<<576,  256, 0, stream>>>(off, cwg, cig);
    k_dcn_mfma    <<<1024, 512, 0, stream>>>(base_t, cwg, cig, wdcn, part2b);
    k_encreduce   <<<2048, 256, 0, stream>>>(part2b, enc_b, enc_t);
    k_fuse_mfma   <<<2048, 256, 0, stream>>>(enc_t, w2, bnp, x, y, out);
}

// Round 14
// 239.497 us; speedup vs baseline: 1.0844x; 1.0837x over previous
//
#include <hip/hip_runtime.h>
#include <math.h>

#define BB 4
#define CH 256
#define CCH 64
#define HH 64
#define WW 64
#define HWN 4096

typedef short s8v __attribute__((ext_vector_type(8)));
typedef float f4v __attribute__((ext_vector_type(4)));

__device__ __forceinline__ float sigmoidf_(float v){ return 1.0f/(1.0f+__expf(-v)); }
__device__ __forceinline__ unsigned short f2bf(float f){
    union{float f; unsigned u;} v; v.f=f;
    unsigned r = v.u + 0x7FFF + ((v.u>>16)&1);
    return (unsigned short)(r>>16);
}
__device__ __forceinline__ float bf2f(unsigned short u){
    union{unsigned u; float f;} v; v.u = ((unsigned)u)<<16; return v.f;
}

// ---------------- K0: ALL weight prep fused (wdcn tap-major | w2 | wofft | bnp) ----------------
__global__ __launch_bounds__(256) void k_prepall(const float* __restrict__ enc_w,
    const float* __restrict__ wew, const float* __restrict__ wfw, const float* __restrict__ ow,
    const float* __restrict__ web, const float* __restrict__ weg, const float* __restrict__ webt,
    const float* __restrict__ wem, const float* __restrict__ wev,
    const float* __restrict__ wfb, const float* __restrict__ wfg, const float* __restrict__ wfbt,
    const float* __restrict__ wfm, const float* __restrict__ wfv,
    unsigned short* __restrict__ wdcn, unsigned short* __restrict__ w2,
    unsigned short* __restrict__ wofft, float* __restrict__ bnp){
    int i = blockIdx.x*256+threadIdx.x;
    if (i < 147456){
        int oc = i/2304, kk = i-oc*2304;
        int k = kk>>8, c = kk&255;
        wdcn[i] = f2bf(enc_w[(size_t)oc*2304 + c*9 + k]);
        return;
    }
    int j = i - 147456;
    if (j < 294912){
        int row = j/576, k = j-row*576;
        int t = k>>6, ic = k&63;
        float v = (row<256)? wew[((row<<6)+ic)*9+t] : wfw[(((row-256)<<6)+ic)*9+t];
        w2[j] = f2bf(v);
        return;
    }
    int m = j - 294912;
    if (m < 73728){
        int ko = m/2304, k = m-ko*2304;
        int t = k>>8, c = k&255;
        wofft[m] = f2bf((ko<27)? ow[(size_t)(ko*256+c)*9+t] : 0.f);
        return;
    }
    int n = m - 73728;
    if (n < 256){
        float ie = weg[n]*rsqrtf(wev[n]+1e-5f);
        float se = webt[n]-wem[n]*ie+web[n]*ie;
        float iff = wfg[n]*rsqrtf(wfv[n]+1e-5f);
        float sf = wfbt[n]-wfm[n]*iff+wfb[n]*iff;
        *(float4*)(bnp+n*4) = make_float4(ie,se,iff,sf);
    }
}

// ---------------- K1: base = x+y, per-(b,c) sum ----------------
__global__ __launch_bounds__(256) void k_base_sum(const float* __restrict__ x, const float* __restrict__ y,
                                                  float* __restrict__ base, float* __restrict__ sums){
    int bc = blockIdx.x, tid = threadIdx.x;
    const float* xp = x + (size_t)bc*HWN;
    const float* yp = y + (size_t)bc*HWN;
    float* bp = base + (size_t)bc*HWN;
    float s = 0.f;
    for (int i=tid;i<HWN;i+=256){ float v = xp[i]+yp[i]; bp[i]=v; s+=v; }
    __shared__ float red[256];
    red[tid]=s; __syncthreads();
    for (int off=128; off>0; off>>=1){ if (tid<off) red[tid]+=red[tid+off]; __syncthreads(); }
    if (tid==0) sums[bc]=red[0];
}

// ---------------- K2: SE MLP -> scale = 1 + sigmoid(relu(mean@w1T)@w2T) ----------------
__global__ __launch_bounds__(256) void k_se(const float* __restrict__ sums, const float* __restrict__ w1,
                                            const float* __restrict__ w2, float* __restrict__ scale){
    int b = blockIdx.x, tid = threadIdx.x;
    __shared__ float sm[256];
    __shared__ float hid[16];
    sm[tid] = sums[b*256+tid]*(1.0f/4096.0f);
    __syncthreads();
    if (tid<16){
        float a=0.f; const float* wp = w1 + tid*256;
        for (int c=0;c<256;c++) a += sm[c]*wp[c];
        hid[tid]=fmaxf(a,0.f);
    }
    __syncthreads();
    float a=0.f; const float* wp = w2 + tid*16;
    #pragma unroll
    for (int j=0;j<16;j++) a += hid[j]*wp[j];
    scale[b*256+tid] = 1.f + sigmoidf_(a);
}

// ---------------- K3: emit base_t bf16 [b][pos][c] = base*scale ----------------
__global__ __launch_bounds__(256) void k_scale_t(const float* __restrict__ base, const float* __restrict__ scale,
                                                 unsigned short* __restrict__ base_t){
    int bid = blockIdx.x;
    int pb = bid&63, cb = (bid>>6)&3, b = bid>>8;
    int tid = threadIdx.x;
    __shared__ unsigned short lt[64*66];
    #pragma unroll
    for (int it=0; it<16; ++it){
        int idx = it*256 + tid;
        int c = idx>>6, p = idx&63;
        size_t gi = ((size_t)(b*256 + cb*64 + c))*4096 + pb*64 + p;
        float v = base[gi] * scale[b*256 + cb*64 + c];
        lt[p*66 + c] = f2bf(v);
    }
    __syncthreads();
    #pragma unroll
    for (int it=0; it<8; ++it){
        int idx = it*256 + tid;   // 0..2047: 64 pos x 32 ch-pairs
        int p = idx>>5, cp = idx&31;
        unsigned lo = lt[p*66 + cp*2], hi = lt[p*66 + cp*2+1];
        *(unsigned*)(base_t + ((size_t)(b*4096 + pb*64 + p))*256 + cb*64 + cp*2) = lo | (hi<<16);
    }
}

// ---------------- K4: offset conv via MFMA: C[32][64 pos], K=2304 tap-major ----------------
__global__ __launch_bounds__(512) void k_offconv_mfma(const unsigned short* __restrict__ base_t,
    const unsigned short* __restrict__ wofft, const float* __restrict__ ob, float* __restrict__ off){
    int bid = blockIdx.x;
    int tIdx = bid&63, b = bid>>6;
    int th = tIdx>>3, tw = tIdx&7;
    int tid = threadIdx.x;
    __shared__ unsigned short plds[3200*8];
    const unsigned short* bt = base_t + (((size_t)b)<<12)*256;
    for (int i=tid; i<3200; i+=512){
        int spot = i>>5, cid = i&31;
        int sy = spot/10, sx = spot - sy*10;
        int gy = th*8 + sy - 1, gx = tw*8 + sx - 1;
        uint4 v = make_uint4(0u,0u,0u,0u);
        if (gy>=0 && gy<HH && gx>=0 && gx<WW)
            v = *(const uint4*)(bt + ((size_t)((gy<<6)+gx))*256 + cid*8);
        int chunk = (spot<<5) | (cid ^ (spot&7));
        *(uint4*)(plds + (chunk<<3)) = v;
    }
    __syncthreads();
    int lane = tid&63, w = tid>>6;
    int rf = w&1, pf = w>>1;
    int col = lane&15, kg = lane>>4;
    int p = pf*16 + col, ly = p>>3, lx = p&7;
    f4v acc = (f4v){0.f,0.f,0.f,0.f};
    #pragma unroll
    for (int j=0;j<9;j++){
        int dy = j/3, dx = j%3;
        int spot = (ly+dy)*10 + lx+dx;
        const unsigned short* arow = wofft + (size_t)(rf*16+col)*2304 + j*256 + kg*8;
        #pragma unroll
        for (int s=0;s<8;s++){
            s8v a = *(const s8v*)(arow + s*32);
            int cid = s*4 + kg;
            s8v bf = *(const s8v*)(plds + (((spot<<5)|(cid^(spot&7)))<<3));
            acc = __builtin_amdgcn_mfma_f32_16x16x32_bf16(a, bf, acc, 0,0,0);
        }
    }
    int gy = th*8+ly, gx = tw*8+lx;
    #pragma unroll
    for (int r=0;r<4;r++){
        int ko = rf*16 + kg*4 + r;
        if (ko < 27)
            off[(((size_t)(b*27+ko))<<12) + (gy<<6) + gx] = acc[r] + ob[ko];
    }
}

// ---------------- K5a: per-(b,k,pos) corner weights/indices ----------------
__global__ __launch_bounds__(256) void k_prep_off(const float* __restrict__ off,
                                                  float4* __restrict__ cwg, int4* __restrict__ cig){
    int i = blockIdx.x*256+threadIdx.x;
    if (i >= 147456) return;
    int b = i/36864, rem = i - b*36864;
    int k = rem>>12, pos = rem&4095;
    int h = pos>>6, p = pos&63;
    const float* op = off + ((size_t)b*27<<12) + pos;
    float dy = op[(size_t)(2*k)<<12];
    float dx = op[(size_t)(2*k+1)<<12];
    float m  = sigmoidf_(op[(size_t)(18+k)<<12]);
    float py = (float)(h + k/3 - 1) + dy;
    float px = (float)(p + (k%3) - 1) + dx;
    float y0 = floorf(py), x0 = floorf(px);
    float fy1 = py - y0, fy0 = 1.f - fy1;
    float fx1 = px - x0, fx0 = 1.f - fx1;
    int iy0 = (int)y0, ix0 = (int)x0;
    bool vy0 = (y0>=0.f)&&(y0<64.f), vy1 = (y0>=-1.f)&&(y0<63.f);
    bool vx0 = (x0>=0.f)&&(x0<64.f), vx1 = (x0>=-1.f)&&(x0<63.f);
    int cy0 = min(max(iy0,0),63), cy1 = min(max(iy0+1,0),63);
    int cx0 = min(max(ix0,0),63), cx1 = min(max(ix0+1,0),63);
    float4 wv; int4 iv;
    wv.x = (vy0&&vx0)? fy0*fx0*m : 0.f;
    wv.y = (vy0&&vx1)? fy0*fx1*m : 0.f;
    wv.z = (vy1&&vx0)? fy1*fx0*m : 0.f;
    wv.w = (vy1&&vx1)? fy1*fx1*m : 0.f;
    iv.x = cy0*WW+cx0; iv.y = cy0*WW+cx1; iv.z = cy1*WW+cx0; iv.w = cy1*WW+cx1;
    cwg[i] = wv; cig[i] = iv;
}

// ---------------- K5b: DCNv2 channel-contiguous sample + MFMA, split-K x4 ----------------
__global__ __launch_bounds__(512) void k_dcn_mfma(const unsigned short* __restrict__ base_t,
    const float4* __restrict__ cwg, const int4* __restrict__ cig,
    const unsigned short* __restrict__ wdcn, unsigned short* __restrict__ part2b){
    int bid = blockIdx.x;
    int cg = bid&3, b = (bid>>2)&3, h = bid>>4;
    int tid = threadIdx.x;
    __shared__ float4 cw4[576];
    __shared__ int4   ci4[576];
    __shared__ unsigned short smp[2][4096];

    for (int i=tid;i<576;i+=512){
        int k = i>>6, p = i&63;
        size_t g = (((size_t)b*9 + k)<<12) + (h<<6) + p;
        cw4[i] = cwg[g];
        ci4[i] = cig[g];
    }
    __syncthreads();

    int pos = tid>>3, cv = tid&7;
    int w = tid>>6, lane = tid&63;
    int mf = w&3, nh = w>>2;
    int col = lane&15, kg = lane>>4;
    f4v acc0 = (f4v){0.f,0.f,0.f,0.f}, acc1 = acc0;
    const unsigned short* bt = base_t + (((size_t)b)<<12)*256 + cg*64 + cv*8;
    const unsigned short* wrow = wdcn + (size_t)(mf*16+col)*2304 + cg*64;

    #pragma unroll
    for (int t=0;t<9;t++){
        float4 wv = cw4[t*64+pos];
        int4  iv = ci4[t*64+pos];
        uint4 r0 = *(const uint4*)(bt + ((size_t)iv.x<<8));
        uint4 r1 = *(const uint4*)(bt + ((size_t)iv.y<<8));
        uint4 r2 = *(const uint4*)(bt + ((size_t)iv.z<<8));
        uint4 r3 = *(const uint4*)(bt + ((size_t)iv.w<<8));
        const unsigned* q0=(const unsigned*)&r0;
        const unsigned* q1=(const unsigned*)&r1;
        const unsigned* q2=(const unsigned*)&r2;
        const unsigned* q3=(const unsigned*)&r3;
        unsigned pk[4];
        #pragma unroll
        for (int d=0;d<4;d++){
            float lo = wv.x*bf2f((unsigned short)(q0[d]&0xFFFFu)) + wv.y*bf2f((unsigned short)(q1[d]&0xFFFFu))
                     + wv.z*bf2f((unsigned short)(q2[d]&0xFFFFu)) + wv.w*bf2f((unsigned short)(q3[d]&0xFFFFu));
            float hi = wv.x*bf2f((unsigned short)(q0[d]>>16)) + wv.y*bf2f((unsigned short)(q1[d]>>16))
                     + wv.z*bf2f((unsigned short)(q2[d]>>16)) + wv.w*bf2f((unsigned short)(q3[d]>>16));
            pk[d] = (unsigned)f2bf(lo) | ((unsigned)f2bf(hi)<<16);
        }
        *(uint4*)(&smp[t&1][0] + (((pos<<3)|(cv^(pos&7)))<<3)) = *(const uint4*)pk;
        __syncthreads();
        const unsigned short* sb = &smp[t&1][0];
        #pragma unroll
        for (int ks=0;ks<2;ks++){
            s8v a = *(const s8v*)(wrow + t*256 + ks*32 + kg*8);
            int cgrp = ks*4+kg;
            int p0 = (nh*2)*16 + col;
            int p1 = p0 + 16;
            s8v b0 = *(const s8v*)(sb + (((p0<<3)|(cgrp^(p0&7)))<<3));
            s8v b1 = *(const s8v*)(sb + (((p1<<3)|(cgrp^(p1&7)))<<3));
            acc0 = __builtin_amdgcn_mfma_f32_16x16x32_bf16(a, b0, acc0, 0,0,0);
            acc1 = __builtin_amdgcn_mfma_f32_16x16x32_bf16(a, b1, acc1, 0,0,0);
        }
    }

    unsigned short* pout = part2b + ((size_t)(cg*BB + b))*(HWN*64);
    #pragma unroll
    for (int j=0;j<2;j++){
        f4v a = j ? acc1 : acc0;
        int posg = (h<<6) + (nh*2+j)*16 + col;
        int oc = mf*16 + kg*4;
        unsigned lo = (unsigned)f2bf(a[0]) | ((unsigned)f2bf(a[1])<<16);
        unsigned hi = (unsigned)f2bf(a[2]) | ((unsigned)f2bf(a[3])<<16);
        *(uint2*)(pout + (size_t)posg*64 + oc) = make_uint2(lo,hi);
    }
}

// ---------------- K5c: sum 4 bf16 partials + bias + relu -> enc_t bf16 [b][pos][oc] ----------------
__global__ __launch_bounds__(256) void k_encreduce(const unsigned short* __restrict__ part2b,
                                                   const float* __restrict__ encb,
                                                   unsigned short* __restrict__ enc_t){
    int i = blockIdx.x*256+threadIdx.x;
    int b = i>>17, rem = i&131071;
    int pos = rem>>5, oc2 = rem&31;
    size_t basei = (((size_t)b<<12) + pos)*64 + oc2*2;
    float s0 = encb[oc2*2], s1 = encb[oc2*2+1];
    #pragma unroll
    for (int cg=0;cg<4;cg++){
        unsigned pv = *(const unsigned*)(part2b + (size_t)cg*1048576 + basei);
        s0 += bf2f((unsigned short)(pv & 0xFFFFu));
        s1 += bf2f((unsigned short)(pv >> 16));
    }
    unsigned short lo = f2bf(fmaxf(s0,0.f));
    unsigned short hi = f2bf(fmaxf(s1,0.f));
    *(unsigned int*)(enc_t + basei) = (unsigned int)lo | ((unsigned int)hi<<16);
}

// ---------------- K6: fused gate convs via MFMA bf16 + BN + sigmoid + blend ----------------
// 512 blocks x 512 thr; block: 64 rows (32 we + 32 wf) x 256 pos (16x16 tile), K=576 tap-major.
// XCD swizzle: sw = xslot + 8*(ocg + 8*(tilehi + 2*b)) so all 8 ocg of a tile share one XCD's L2.
__global__ __launch_bounds__(512) void k_fuse_mfma(const unsigned short* __restrict__ enc_t,
    const unsigned short* __restrict__ w2, const float* __restrict__ bnp,
    const float* __restrict__ x, const float* __restrict__ y, float* __restrict__ out){
    int sw = blockIdx.x;
    int xslot = sw&7, inner = sw>>3;
    int ocg = inner&7, hi2 = inner>>3;      // hi2 in [0,8)
    int tile = ((hi2&1)<<3) | xslot;        // 16 tiles
    int b = hi2>>1;
    int h0 = (tile>>2)<<4, w0 = (tile&3)<<4;
    int tid = threadIdx.x;
    __shared__ unsigned short elds[324*64];

    const unsigned short* ebase = enc_t + (((size_t)b)<<12)*64;
    #pragma unroll
    for (int kk=0;kk<6;kk++){
        int i = tid + kk*512;
        if (i < 2592){
            int sp = i>>3, icg = i&7;
            int sy = sp/18, sx = sp - sy*18;
            int py = h0+sy-1, px = w0+sx-1;
            uint4 v = make_uint4(0u,0u,0u,0u);
            if (py>=0 && py<HH && px>=0 && px<WW)
                v = *(const uint4*)(ebase + (size_t)((py<<6)+px)*64 + (icg<<3));
            int chunk = ((sp<<3) | icg) ^ (sp&7);
            *(uint4*)(elds + (chunk<<3)) = v;
        }
    }
    __syncthreads();

    int lane = tid&63, w = tid>>6;
    int col = lane&15, kg = lane>>4;
    f4v acc[4][2];
    #pragma unroll
    for (int rf=0;rf<4;rf++)
        #pragma unroll
        for (int pf=0;pf<2;pf++) acc[rf][pf] = (f4v){0.f,0.f,0.f,0.f};

    #pragma unroll
    for (int t=0;t<18;t++){
        const int j = t>>1, ih = t&1;
        const int dy = j/3-1, dx = j%3-1;
        s8v af[4];
        #pragma unroll
        for (int rf=0;rf<4;rf++){
            int row = (rf<2 ? ocg*32 + rf*16 : 256 + ocg*32 + (rf-2)*16) + col;
            af[rf] = *(const s8v*)(w2 + (size_t)row*576 + t*32 + kg*8);
        }
        s8v bfr[2];
        #pragma unroll
        for (int pf=0;pf<2;pf++){
            int tyc = w*2+pf;
            int sp = (tyc+dy+1)*18 + (col+dx+1);
            int chunk = ((sp<<3) | (ih*4+kg)) ^ (sp&7);
            bfr[pf] = *(const s8v*)(elds + (chunk<<3));
        }
        #pragma unroll
        for (int rf=0;rf<4;rf++)
            #pragma unroll
            for (int pf=0;pf<2;pf++)
                acc[rf][pf] = __builtin_amdgcn_mfma_f32_16x16x32_bf16(af[rf], bfr[pf], acc[rf][pf], 0,0,0);
    }

    #pragma unroll
    for (int rf=0;rf<2;rf++){
        #pragma unroll
        for (int pf=0;pf<2;pf++){
            int tyc = w*2+pf;
            int py = h0+tyc, px = w0+col;
            #pragma unroll
            for (int r=0;r<4;r++){
                int oc = ocg*32 + rf*16 + kg*4 + r;
                float4 bn = *(const float4*)(bnp + oc*4);
                float ve = sigmoidf_(acc[rf  ][pf][r]*bn.x + bn.y);
                float vf = sigmoidf_(acc[rf+2][pf][r]*bn.z + bn.w);
                size_t oi = (((size_t)((b<<8)+oc))<<12) + (py<<6) + px;
                out[oi] = ve*x[oi] + vf*y[oi];
            }
        }
    }
}

extern "C" void kernel_launch(void* const* d_in, const int* in_sizes, int n_in,
                              void* d_out, int out_size, void* d_ws, size_t ws_size,
                              hipStream_t stream) {
    const float* x     = (const float*)d_in[0];
    const float* y     = (const float*)d_in[1];
    const float* se_w1 = (const float*)d_in[2];
    const float* se_w2 = (const float*)d_in[3];
    const float* off_w = (const float*)d_in[4];
    const float* off_b = (const float*)d_in[5];
    const float* enc_w = (const float*)d_in[6];
    const float* enc_b = (const float*)d_in[7];
    const float* we_w  = (const float*)d_in[8];
    const float* we_b  = (const float*)d_in[9];
    const float* we_g  = (const float*)d_in[10];
    const float* we_bt = (const float*)d_in[11];
    const float* we_m  = (const float*)d_in[12];
    const float* we_v  = (const float*)d_in[13];
    const float* wf_w  = (const float*)d_in[14];
    const float* wf_b  = (const float*)d_in[15];
    const float* wf_g  = (const float*)d_in[16];
    const float* wf_bt = (const float*)d_in[17];
    const float* wf_m  = (const float*)d_in[18];
    const float* wf_v  = (const float*)d_in[19];
    float* out = (float*)d_out;

    float* ws     = (float*)d_ws;
    float* base   = ws;                       // 4194304 f
    float* off    = base + 4194304;           // 442368 f
    float* encT_f = off  + 442368;            // 524288 f (1048576 ush)
    float* sums   = encT_f + 524288;          // 1024 f
    float* scale  = sums + 1024;              // 1024 f
    float* wdcn_f = scale + 1024;             // 73728 f (147456 ush)
    float* w2f    = wdcn_f + 73728;           // 147456 f (294912 ush)
    float* bnp    = w2f  + 147456;            // 1024 f
    float* wofft_f= bnp  + 1024;              // 36864 f (73728 ush)
    float* cw_f   = wofft_f + 36864;          // 589824 f (147456 float4)
    float* ci_f   = cw_f + 589824;            // 589824 f (147456 int4)
    unsigned short* enc_t = (unsigned short*)encT_f;
    unsigned short* wdcn  = (unsigned short*)wdcn_f;
    unsigned short* w2    = (unsigned short*)w2f;
    unsigned short* wofft = (unsigned short*)wofft_f;
    float4* cwg = (float4*)cw_f;
    int4*   cig = (int4*)ci_f;
    // d_out scratch, two disjoint 8.39MB halves:
    unsigned short* base_t = (unsigned short*)out;            // k_scale_t -> k_offconv/k_dcn
    unsigned short* part2b = (unsigned short*)out + 4194304;  // k_dcn -> k_encreduce

    k_prepall     <<<2018, 256, 0, stream>>>(enc_w, we_w, wf_w, off_w,
                                             we_b, we_g, we_bt, we_m, we_v,
                                             wf_b, wf_g, wf_bt, wf_m, wf_v,
                                             wdcn, w2, wofft, bnp);
    k_base_sum    <<<1024, 256, 0, stream>>>(x, y, base, sums);
    k_se          <<<4,    256, 0, stream>>>(sums, se_w1, se_w2, scale);
    k_scale_t     <<<1024, 256, 0, stream>>>(base, scale, base_t);
    k_offconv_mfma<<<256,  512, 0, stream>>>(base_t, wofft, off_b, off);
    k_prep_off    <<<576,  256, 0, stream>>>(off, cwg, cig);
    k_dcn_mfma    <<<1024, 512, 0, stream>>>(base_t, cwg, cig, wdcn, part2b);
    k_encreduce   <<<2048, 256, 0, stream>>>(part2b, enc_b, enc_t);
    k_fuse_mfma   <<<512,  512, 0, stream>>>(enc_t, w2, bnp, x, y, out);
}